// Round 3
// baseline (251.730 us; speedup 1.0000x reference)
//
#include <hip/hip_runtime.h>
#include <hip/hip_bf16.h>
#include <cstdint>
#include <cstddef>

typedef unsigned int uint;
typedef unsigned short ushort;

constexpr int Bn = 4, Nn = 2048, Cc = 1024, Hh = 16;
constexpr int ROWS = Bn * Nn;           // 8192
constexpr int QKVC = 3 * Cc;            // 3072
constexpr float SL2 = 0.18033688011118f; // D^-0.5 * log2(e)

typedef __bf16 bf16_t;
typedef bf16_t bf16x8 __attribute__((ext_vector_type(8)));
typedef float f32x4 __attribute__((ext_vector_type(4)));

__device__ __forceinline__ ushort f2bf(float f) {
  union { __bf16 b; ushort u; } cv;
  cv.b = (__bf16)f;
  return cv.u;
}
__device__ __forceinline__ float exp2v(float x) { return __builtin_exp2f(x); }

__device__ __forceinline__ void gload_lds16(const void* g, void* l) {
  __builtin_amdgcn_global_load_lds(
      (const __attribute__((address_space(1))) void*)g,
      (__attribute__((address_space(3))) void*)l, 16, 0, 0);
}

// ---------------- f32 -> bf16 elementwise (8 elems/thread, exact cover) ----
__global__ __launch_bounds__(256) void cvt_bf16_kernel(
    const float* __restrict__ in, ushort* __restrict__ out) {
  int i = blockIdx.x * 256 + threadIdx.x;
  const float4* ip = (const float4*)in;
  float4 a = ip[i * 2], b = ip[i * 2 + 1];
  uint4 w;
  w.x = (uint)f2bf(a.x) | ((uint)f2bf(a.y) << 16);
  w.y = (uint)f2bf(a.z) | ((uint)f2bf(a.w) << 16);
  w.z = (uint)f2bf(b.x) | ((uint)f2bf(b.y) << 16);
  w.w = (uint)f2bf(b.z) | ((uint)f2bf(b.w) << 16);
  ((uint4*)out)[i] = w;
}

// ---------------- transpose + convert: W[K][N] f32 -> Wt[N][K] bf16 --------
__global__ __launch_bounds__(256) void transpose_cvt_kernel(
    const float* __restrict__ W, ushort* __restrict__ Wt, int K, int N) {
  __shared__ float tile[64][65];
  const int n0 = blockIdx.x * 64, k0 = blockIdx.y * 64;
  const int tid = threadIdx.x;
#pragma unroll
  for (int it = 0; it < 16; it++) {
    int idx = tid + it * 256;
    int r = idx >> 6, c = idx & 63;
    tile[r][c] = W[(size_t)(k0 + r) * N + n0 + c];
  }
  __syncthreads();
#pragma unroll
  for (int it = 0; it < 16; it++) {
    int idx = tid + it * 256;
    int r = idx >> 6, c = idx & 63;
    Wt[(size_t)(n0 + r) * K + k0 + c] = f2bf(tile[c][r]);
  }
}

// ---------------- 128x128 MFMA GEMM (m97 structure): C = A * Bt^T -----------
template <int MODE>
__global__ __launch_bounds__(256) void gemm128_kernel(
    const ushort* __restrict__ A, const ushort* __restrict__ Bt,
    void* __restrict__ Cout, void* __restrict__ Vout,
    const float* __restrict__ bias, int M, int N, int K) {
  __shared__ ushort As[128 * 32];
  __shared__ ushort Bs[128 * 32];
  const int tid = threadIdx.x;
  const int lane = tid & 63;
  const int wid = tid >> 6;
  const int wm = wid >> 1, wn = wid & 1;          // 2x2 wave grid
  const int l16 = lane & 15, g = lane >> 4;
  const int n0 = blockIdx.x * 128, m0 = blockIdx.y * 128;

  const int c0 = tid, c1 = tid + 256;
  const ushort* Ab = A + (size_t)m0 * K;
  const ushort* Bb = Bt + (size_t)n0 * K;
  f32x4 acc[4][4] = {};

  for (int k0 = 0; k0 < K; k0 += 32) {
    gload_lds16(Ab + (size_t)(c0 >> 2) * K + k0 + (c0 & 3) * 8, As + c0 * 8);
    gload_lds16(Ab + (size_t)(c1 >> 2) * K + k0 + (c1 & 3) * 8, As + c1 * 8);
    gload_lds16(Bb + (size_t)(c0 >> 2) * K + k0 + (c0 & 3) * 8, Bs + c0 * 8);
    gload_lds16(Bb + (size_t)(c1 >> 2) * K + k0 + (c1 & 3) * 8, Bs + c1 * 8);
    __syncthreads();
    bf16x8 af[4], bfr[4];
#pragma unroll
    for (int mf = 0; mf < 4; mf++)
      af[mf] = *(const bf16x8*)(As + (wm * 64 + mf * 16 + l16) * 32 + g * 8);
#pragma unroll
    for (int nf = 0; nf < 4; nf++)
      bfr[nf] = *(const bf16x8*)(Bs + (wn * 64 + nf * 16 + l16) * 32 + g * 8);
#pragma unroll
    for (int mf = 0; mf < 4; mf++)
#pragma unroll
      for (int nf = 0; nf < 4; nf++)
        acc[mf][nf] = __builtin_amdgcn_mfma_f32_16x16x32_bf16(af[mf], bfr[nf], acc[mf][nf], 0, 0, 0);
    __syncthreads();
  }

#pragma unroll
  for (int mf = 0; mf < 4; mf++) {
    const int orow0 = m0 + wm * 64 + mf * 16 + g * 4;
#pragma unroll
    for (int nf = 0; nf < 4; nf++) {
      int col = n0 + wn * 64 + nf * 16 + l16;
      if (MODE == 0) {
        if (col < 2048) {
#pragma unroll
          for (int r = 0; r < 4; r++)
            ((ushort*)Cout)[(size_t)(orow0 + r) * 2048 + col] = f2bf(acc[mf][nf][r]);
        } else {
          int hh = (col - 2048) >> 6, dd = (col - 2048) & 63;
          int bb = orow0 >> 11, nn = orow0 & 2047;
          ushort4 w;
          w.x = f2bf(acc[mf][nf][0]); w.y = f2bf(acc[mf][nf][1]);
          w.z = f2bf(acc[mf][nf][2]); w.w = f2bf(acc[mf][nf][3]);
          *(ushort4*)((ushort*)Vout + ((size_t)(bb * 16 + hh) * 64 + dd) * 2048 + nn) = w;
        }
      } else {
#pragma unroll
        for (int r = 0; r < 4; r++)
          ((float*)Cout)[(size_t)(orow0 + r) * N + col] = acc[mf][nf][r] + bias[col];
      }
    }
  }
}

// ---------------- MFMA flash attention (QBLK=64/wave, in-register P) --------
// qk:  bf16 [8192][2048]  (cols 0-1023 Q, 1024-2047 K; col = h*64+d)
// vt:  bf16 [64 bh][64 d][2048 n]
// obf: bf16 [8192][1024]
//
// Each wave owns 64 q rows (4 x 16); block = 4 waves = 256 q rows.
// K/V fragments are reused across all 4 qh sub-tiles -> per-wave LDS reads
// unchanged while waves halve => CU LDS-read traffic halves vs QBLK=32.
// P stays in registers (cvt_pk + permlane32/16_swap transpose); l via
// mfma(pa, ones) into lacc.
__global__ __launch_bounds__(256, 2) void flash_mfma_kernel(
    const ushort* __restrict__ qk, const ushort* __restrict__ vt,
    ushort* __restrict__ obf) {
  __shared__ ushort Ks[2][64 * 64];       // double-buffered [kv][d], swizzled
  __shared__ ushort Vs[2][64 * 64];       // double-buffered [d][kv], swizzled
  const int tid = threadIdx.x;
  const int lane = tid & 63, wid = tid >> 6;
  const int l16 = lane & 15, g = lane >> 4;
  const int bh = blockIdx.y, b = bh >> 4, h = bh & 15;
  const int q0 = blockIdx.x * 256 + wid * 64;

  // staging chunk ids (c in [0,512): row=c>>3, colc=c&7, XOR-swizzled source)
  const int sc0 = tid, sc1 = tid + 256;
  const int sr0 = sc0 >> 3, scol0 = ((sc0 & 7) ^ (sr0 & 7)) * 8;
  const int sr1 = sc1 >> 3, scol1 = ((sc1 & 7) ^ (sr1 & 7)) * 8;
  const ushort* Kbase = qk + (size_t)b * Nn * 2048 + 1024 + h * 64;
  const ushort* Vbase = vt + (size_t)bh * 64 * 2048;

#define STAGE(buf, kv0)                                                       \
  do {                                                                        \
    gload_lds16(Kbase + (size_t)((kv0) + sr0) * 2048 + scol0,                 \
                &Ks[buf][0] + sc0 * 8);                                       \
    gload_lds16(Kbase + (size_t)((kv0) + sr1) * 2048 + scol1,                 \
                &Ks[buf][0] + sc1 * 8);                                       \
    gload_lds16(Vbase + (size_t)sr0 * 2048 + (kv0) + scol0,                   \
                &Vs[buf][0] + sc0 * 8);                                       \
    gload_lds16(Vbase + (size_t)sr1 * 2048 + (kv0) + scol1,                   \
                &Vs[buf][0] + sc1 * 8);                                       \
  } while (0)

  // hoist Q fragments: 64 q rows as 4 x 16
  bf16x8 qf[4][2];
#pragma unroll
  for (int qh = 0; qh < 4; qh++)
#pragma unroll
    for (int kc = 0; kc < 2; kc++)
      qf[qh][kc] = *(const bf16x8*)(
          qk + (size_t)(b * Nn + q0 + qh * 16 + l16) * 2048 + h * 64 + kc * 32 + g * 8);

  // ones B-fragment (bf16 1.0 = 0x3F80)
  union { ushort us[8]; bf16x8 v; } onesu;
#pragma unroll
  for (int j = 0; j < 8; j++) onesu.us[j] = 0x3F80;
  const bf16x8 ones = onesu.v;

  f32x4 oacc[4][4] = {};
  f32x4 lacc[4] = {};
  float mrun[4] = {-INFINITY, -INFINITY, -INFINITY, -INFINITY};  // log2 domain

  STAGE(0, 0);                             // prefetch tile 0

  for (int t = 0; t < Nn / 64; ++t) {
    const int cur = t & 1;
    // tile-t loads were issued a full tile ago -> no actual wait cost
    asm volatile("s_waitcnt vmcnt(0)" ::: "memory");
    __builtin_amdgcn_s_barrier();          // data-ready + WAR guard in one
    asm volatile("" ::: "memory");
    if (t < Nn / 64 - 1) STAGE(cur ^ 1, (t + 1) * 64);  // overlaps whole tile

    const ushort* Kc = &Ks[cur][0];
    const ushort* Vc = &Vs[cur][0];

    // S^T[kv][q] = K * Q^T   (kf reused across the 4 qh sub-tiles)
    f32x4 sacc[4][4] = {};
    __builtin_amdgcn_s_setprio(1);
#pragma unroll
    for (int kc = 0; kc < 2; kc++) {
#pragma unroll
      for (int jc = 0; jc < 4; jc++) {
        int row = jc * 16 + l16;
        bf16x8 kf = *(const bf16x8*)(Kc + row * 64 + ((kc * 32 + g * 8) ^ ((row & 7) << 3)));
#pragma unroll
        for (int qh = 0; qh < 4; qh++)
          sacc[qh][jc] = __builtin_amdgcn_mfma_f32_16x16x32_bf16(kf, qf[qh][kc], sacc[qh][jc], 0, 0, 0);
      }
    }
    __builtin_amdgcn_s_setprio(0);

    // online softmax (log2 domain); lane owns q-col = qh*16+l16
    float pmax[4];
#pragma unroll
    for (int qh = 0; qh < 4; qh++) {
      float mj0 = fmaxf(fmaxf(fmaxf(sacc[qh][0][0], sacc[qh][0][1]), sacc[qh][0][2]), sacc[qh][0][3]);
      float mj1 = fmaxf(fmaxf(fmaxf(sacc[qh][1][0], sacc[qh][1][1]), sacc[qh][1][2]), sacc[qh][1][3]);
      float mj2 = fmaxf(fmaxf(fmaxf(sacc[qh][2][0], sacc[qh][2][1]), sacc[qh][2][2]), sacc[qh][2][3]);
      float mj3 = fmaxf(fmaxf(fmaxf(sacc[qh][3][0], sacc[qh][3][1]), sacc[qh][3][2]), sacc[qh][3][3]);
      float mx = fmaxf(fmaxf(fmaxf(mj0, mj1), mj2), mj3);
      mx = fmaxf(mx, __shfl_xor(mx, 16));
      mx = fmaxf(mx, __shfl_xor(mx, 32));
      pmax[qh] = mx * SL2;
    }
    bool need = false;
#pragma unroll
    for (int qh = 0; qh < 4; qh++) need = need || (pmax[qh] > mrun[qh] + 8.f);
    if (__any(need)) {
#pragma unroll
      for (int qh = 0; qh < 4; qh++) {
        float mnew = fmaxf(mrun[qh], pmax[qh]);
        float alpha = exp2v(mrun[qh] - mnew);
        mrun[qh] = mnew;
#pragma unroll
        for (int r = 0; r < 4; r++) {
          float ar = __shfl(alpha, g * 4 + r);
#pragma unroll
          for (int dc = 0; dc < 4; dc++) oacc[qh][dc][r] *= ar;
          lacc[qh][r] *= ar;
        }
      }
    }

    // exp2 + pack to bf16 pairs + in-register transpose to PV A-fragments
    bf16x8 pa[4][2];
#pragma unroll
    for (int qh = 0; qh < 4; qh++) {
      uint pk_[4][2];
#pragma unroll
      for (int jc = 0; jc < 4; jc++) {
        float p0 = exp2v(fmaf(sacc[qh][jc][0], SL2, -mrun[qh]));
        float p1 = exp2v(fmaf(sacc[qh][jc][1], SL2, -mrun[qh]));
        float p2 = exp2v(fmaf(sacc[qh][jc][2], SL2, -mrun[qh]));
        float p3 = exp2v(fmaf(sacc[qh][jc][3], SL2, -mrun[qh]));
        asm("v_cvt_pk_bf16_f32 %0, %1, %2" : "=v"(pk_[jc][0]) : "v"(p0), "v"(p1));
        asm("v_cvt_pk_bf16_f32 %0, %1, %2" : "=v"(pk_[jc][1]) : "v"(p2), "v"(p3));
      }
#pragma unroll
      for (int kc = 0; kc < 2; kc++) {
        uint a0 = pk_[kc * 2][0], b0 = pk_[kc * 2 + 1][0];
        asm("v_permlane32_swap_b32 %0, %1" : "+v"(a0), "+v"(b0));
        asm("v_permlane16_swap_b32 %0, %1" : "+v"(a0), "+v"(b0));
        uint a1 = pk_[kc * 2][1], b1 = pk_[kc * 2 + 1][1];
        asm("v_permlane32_swap_b32 %0, %1" : "+v"(a1), "+v"(b1));
        asm("v_permlane16_swap_b32 %0, %1" : "+v"(a1), "+v"(b1));
        union { uint4 u; bf16x8 v; } cv;
        cv.u.x = a0; cv.u.y = a1; cv.u.z = b0; cv.u.w = b1;
        pa[qh][kc] = cv.v;
      }
    }

    // O[q][d] += P[q][kv] * Vt[d][kv]^T ; l += P * ones  (vf reused over qh)
    __builtin_amdgcn_s_setprio(1);
#pragma unroll
    for (int kc = 0; kc < 2; kc++) {
#pragma unroll
      for (int dc = 0; dc < 4; dc++) {
        int row = dc * 16 + l16;
        bf16x8 vf = *(const bf16x8*)(Vc + row * 64 + ((kc * 32 + g * 8) ^ ((row & 7) << 3)));
#pragma unroll
        for (int qh = 0; qh < 4; qh++)
          oacc[qh][dc] = __builtin_amdgcn_mfma_f32_16x16x32_bf16(pa[qh][kc], vf, oacc[qh][dc], 0, 0, 0);
      }
#pragma unroll
      for (int qh = 0; qh < 4; qh++)
        lacc[qh] = __builtin_amdgcn_mfma_f32_16x16x32_bf16(pa[qh][kc], ones, lacc[qh], 0, 0, 0);
    }
    __builtin_amdgcn_s_setprio(0);
  }
#undef STAGE

  // epilogue: lacc[qh][r] is l for q-row g*4+r -- same domain as oacc rows
#pragma unroll
  for (int qh = 0; qh < 4; qh++) {
    f32x4 linv;
#pragma unroll
    for (int r = 0; r < 4; r++) linv[r] = 1.f / lacc[qh][r];
#pragma unroll
    for (int r = 0; r < 4; r++) {
      int grow = b * Nn + q0 + qh * 16 + g * 4 + r;
      ushort* op = obf + (size_t)grow * Cc + h * 64 + l16;
#pragma unroll
      for (int dc = 0; dc < 4; dc++)
        op[dc * 16] = f2bf(oacc[qh][dc][r] * linv[r]);
    }
  }
}

// ---------------------------------------------------------------------------
extern "C" void kernel_launch(void* const* d_in, const int* in_sizes, int n_in,
                              void* d_out, int out_size, void* d_ws, size_t ws_size,
                              hipStream_t stream) {
  const float* x      = (const float*)d_in[0];
  const float* w_qkv  = (const float*)d_in[1];
  const float* w_proj = (const float*)d_in[2];
  const float* b_proj = (const float*)d_in[3];
  float* out = (float*)d_out;

  char* ws = (char*)d_ws;
  ushort* Xbf    = (ushort*)(ws);                        // 16.8 MB
  ushort* WqkvT  = (ushort*)(ws + (16u << 20));          // 6.3 MB
  ushort* WprojT = (ushort*)(ws + (22u << 20));          // 2.1 MB
  ushort* QKbf   = (ushort*)(ws + (24u << 20));          // 33.6 MB
  ushort* Vtg    = (ushort*)(ws + (56u << 20));          // 16.8 MB
  ushort* Obf    = (ushort*)(ws + (72u << 20));          // 16.8 MB (ends 88 MB)

  cvt_bf16_kernel<<<4096, 256, 0, stream>>>(x, Xbf);
  transpose_cvt_kernel<<<dim3(QKVC / 64, Cc / 64), 256, 0, stream>>>(w_qkv, WqkvT, Cc, QKVC);
  transpose_cvt_kernel<<<dim3(Cc / 64, Cc / 64), 256, 0, stream>>>(w_proj, WprojT, Cc, Cc);
  gemm128_kernel<0><<<dim3(QKVC / 128, ROWS / 128), 256, 0, stream>>>(
      Xbf, WqkvT, QKbf, Vtg, nullptr, ROWS, QKVC, Cc);
  flash_mfma_kernel<<<dim3(Nn / 256, Bn * Hh), 256, 0, stream>>>(QKbf, Vtg, Obf);
  gemm128_kernel<1><<<dim3(Cc / 128, ROWS / 128), 256, 0, stream>>>(
      Obf, WprojT, out, nullptr, b_proj, ROWS, Cc, Cc);
}

// Round 4
// 245.705 us; speedup vs baseline: 1.0245x; 1.0245x over previous
//
#include <hip/hip_runtime.h>
#include <hip/hip_bf16.h>
#include <cstdint>
#include <cstddef>

typedef unsigned int uint;
typedef unsigned short ushort;

constexpr int Bn = 4, Nn = 2048, Cc = 1024, Hh = 16;
constexpr int ROWS = Bn * Nn;           // 8192
constexpr int QKVC = 3 * Cc;            // 3072
constexpr float SL2 = 0.18033688011118f; // D^-0.5 * log2(e)

typedef __bf16 bf16_t;
typedef bf16_t bf16x8 __attribute__((ext_vector_type(8)));
typedef float f32x4 __attribute__((ext_vector_type(4)));

__device__ __forceinline__ ushort f2bf(float f) {
  union { __bf16 b; ushort u; } cv;
  cv.b = (__bf16)f;
  return cv.u;
}
__device__ __forceinline__ float exp2v(float x) { return __builtin_exp2f(x); }

__device__ __forceinline__ void gload_lds16(const void* g, void* l) {
  __builtin_amdgcn_global_load_lds(
      (const __attribute__((address_space(1))) void*)g,
      (__attribute__((address_space(3))) void*)l, 16, 0, 0);
}

// ---------------- f32 -> bf16 elementwise (8 elems/thread, exact cover) ----
__global__ __launch_bounds__(256) void cvt_bf16_kernel(
    const float* __restrict__ in, ushort* __restrict__ out) {
  int i = blockIdx.x * 256 + threadIdx.x;
  const float4* ip = (const float4*)in;
  float4 a = ip[i * 2], b = ip[i * 2 + 1];
  uint4 w;
  w.x = (uint)f2bf(a.x) | ((uint)f2bf(a.y) << 16);
  w.y = (uint)f2bf(a.z) | ((uint)f2bf(a.w) << 16);
  w.z = (uint)f2bf(b.x) | ((uint)f2bf(b.y) << 16);
  w.w = (uint)f2bf(b.z) | ((uint)f2bf(b.w) << 16);
  ((uint4*)out)[i] = w;
}

// ---------------- transpose + convert: W[K][N] f32 -> Wt[N][K] bf16 --------
__global__ __launch_bounds__(256) void transpose_cvt_kernel(
    const float* __restrict__ W, ushort* __restrict__ Wt, int K, int N) {
  __shared__ float tile[64][65];
  const int n0 = blockIdx.x * 64, k0 = blockIdx.y * 64;
  const int tid = threadIdx.x;
#pragma unroll
  for (int it = 0; it < 16; it++) {
    int idx = tid + it * 256;
    int r = idx >> 6, c = idx & 63;
    tile[r][c] = W[(size_t)(k0 + r) * N + n0 + c];
  }
  __syncthreads();
#pragma unroll
  for (int it = 0; it < 16; it++) {
    int idx = tid + it * 256;
    int r = idx >> 6, c = idx & 63;
    Wt[(size_t)(n0 + r) * K + k0 + c] = f2bf(tile[c][r]);
  }
}

// ---------------- 128x128 MFMA GEMM (m97 structure): C = A * Bt^T -----------
template <int MODE>
__global__ __launch_bounds__(256) void gemm128_kernel(
    const ushort* __restrict__ A, const ushort* __restrict__ Bt,
    void* __restrict__ Cout, void* __restrict__ Vout,
    const float* __restrict__ bias, int M, int N, int K) {
  __shared__ ushort As[128 * 32];
  __shared__ ushort Bs[128 * 32];
  const int tid = threadIdx.x;
  const int lane = tid & 63;
  const int wid = tid >> 6;
  const int wm = wid >> 1, wn = wid & 1;          // 2x2 wave grid
  const int l16 = lane & 15, g = lane >> 4;
  const int n0 = blockIdx.x * 128, m0 = blockIdx.y * 128;

  const int c0 = tid, c1 = tid + 256;
  const ushort* Ab = A + (size_t)m0 * K;
  const ushort* Bb = Bt + (size_t)n0 * K;
  f32x4 acc[4][4] = {};

  for (int k0 = 0; k0 < K; k0 += 32) {
    gload_lds16(Ab + (size_t)(c0 >> 2) * K + k0 + (c0 & 3) * 8, As + c0 * 8);
    gload_lds16(Ab + (size_t)(c1 >> 2) * K + k0 + (c1 & 3) * 8, As + c1 * 8);
    gload_lds16(Bb + (size_t)(c0 >> 2) * K + k0 + (c0 & 3) * 8, Bs + c0 * 8);
    gload_lds16(Bb + (size_t)(c1 >> 2) * K + k0 + (c1 & 3) * 8, Bs + c1 * 8);
    __syncthreads();
    bf16x8 af[4], bfr[4];
#pragma unroll
    for (int mf = 0; mf < 4; mf++)
      af[mf] = *(const bf16x8*)(As + (wm * 64 + mf * 16 + l16) * 32 + g * 8);
#pragma unroll
    for (int nf = 0; nf < 4; nf++)
      bfr[nf] = *(const bf16x8*)(Bs + (wn * 64 + nf * 16 + l16) * 32 + g * 8);
#pragma unroll
    for (int mf = 0; mf < 4; mf++)
#pragma unroll
      for (int nf = 0; nf < 4; nf++)
        acc[mf][nf] = __builtin_amdgcn_mfma_f32_16x16x32_bf16(af[mf], bfr[nf], acc[mf][nf], 0, 0, 0);
    __syncthreads();
  }

#pragma unroll
  for (int mf = 0; mf < 4; mf++) {
    const int orow0 = m0 + wm * 64 + mf * 16 + g * 4;
#pragma unroll
    for (int nf = 0; nf < 4; nf++) {
      int col = n0 + wn * 64 + nf * 16 + l16;
      if (MODE == 0) {
        if (col < 2048) {
#pragma unroll
          for (int r = 0; r < 4; r++)
            ((ushort*)Cout)[(size_t)(orow0 + r) * 2048 + col] = f2bf(acc[mf][nf][r]);
        } else {
          int hh = (col - 2048) >> 6, dd = (col - 2048) & 63;
          int bb = orow0 >> 11, nn = orow0 & 2047;
          ushort4 w;
          w.x = f2bf(acc[mf][nf][0]); w.y = f2bf(acc[mf][nf][1]);
          w.z = f2bf(acc[mf][nf][2]); w.w = f2bf(acc[mf][nf][3]);
          *(ushort4*)((ushort*)Vout + ((size_t)(bb * 16 + hh) * 64 + dd) * 2048 + nn) = w;
        }
      } else {
#pragma unroll
        for (int r = 0; r < 4; r++)
          ((float*)Cout)[(size_t)(orow0 + r) * N + col] = acc[mf][nf][r] + bias[col];
      }
    }
  }
}

// ---------------- MFMA flash attention (QBLK=32, depth-2 prefetch, XCD) -----
// qk:  bf16 [8192][2048]  (cols 0-1023 Q, 1024-2047 K; col = h*64+d)
// vt:  bf16 [64 bh][64 d][2048 n]
// obf: bf16 [8192][1024]
//
// R2 compute structure (in-register P via cvt_pk + permlane swaps, l via
// mfma(pa,ones)) + two latency fixes:
//  * XCD-aware bijective remap: all 16 q-blocks of one bh land on the same
//    XCD -> staged K/V loads become L2 hits, HBM fetch ~once per XCD.
//  * Triple-buffered K/V (48 KB), prefetch depth 2: loads issued 2 tiles
//    ahead, wait vmcnt(4) in steady state (one STAGE = 4 loads in flight).
__global__ __launch_bounds__(256, 3) void flash_mfma_kernel(
    const ushort* __restrict__ qk, const ushort* __restrict__ vt,
    ushort* __restrict__ obf) {
  __shared__ ushort Ks[3][64 * 64];       // triple-buffered [kv][d], swizzled
  __shared__ ushort Vs[3][64 * 64];       // triple-buffered [d][kv], swizzled
  const int tid = threadIdx.x;
  const int lane = tid & 63, wid = tid >> 6;
  const int l16 = lane & 15, g = lane >> 4;

  // XCD-aware bijective remap of (x, bh). grid = (16, 64); HW round-robins
  // flat id across 8 XCDs (xcd ~ f&7): give each XCD 8 whole bh values.
  const int f = blockIdx.x + (int)(gridDim.x * blockIdx.y);
  const int xcd = f & 7, slot = f >> 3;
  const int bh = xcd * 8 + (slot >> 4);
  const int qx = slot & 15;
  const int b = bh >> 4, h = bh & 15;
  const int q0 = qx * 128 + wid * 32;

  // staging chunk ids (c in [0,512): row=c>>3, colc=c&7, XOR-swizzled source)
  const int sc0 = tid, sc1 = tid + 256;
  const int sr0 = sc0 >> 3, scol0 = ((sc0 & 7) ^ (sr0 & 7)) * 8;
  const int sr1 = sc1 >> 3, scol1 = ((sc1 & 7) ^ (sr1 & 7)) * 8;
  const ushort* Kbase = qk + (size_t)b * Nn * 2048 + 1024 + h * 64;
  const ushort* Vbase = vt + (size_t)bh * 64 * 2048;

#define STAGE(buf, kv0)                                                       \
  do {                                                                        \
    gload_lds16(Kbase + (size_t)((kv0) + sr0) * 2048 + scol0,                 \
                &Ks[buf][0] + sc0 * 8);                                       \
    gload_lds16(Kbase + (size_t)((kv0) + sr1) * 2048 + scol1,                 \
                &Ks[buf][0] + sc1 * 8);                                       \
    gload_lds16(Vbase + (size_t)sr0 * 2048 + (kv0) + scol0,                   \
                &Vs[buf][0] + sc0 * 8);                                       \
    gload_lds16(Vbase + (size_t)sr1 * 2048 + (kv0) + scol1,                   \
                &Vs[buf][0] + sc1 * 8);                                       \
  } while (0)

  // hoist Q fragments
  bf16x8 qf[2][2];
#pragma unroll
  for (int qh = 0; qh < 2; qh++)
#pragma unroll
    for (int kc = 0; kc < 2; kc++)
      qf[qh][kc] = *(const bf16x8*)(
          qk + (size_t)(b * Nn + q0 + qh * 16 + l16) * 2048 + h * 64 + kc * 32 + g * 8);

  // ones B-fragment (bf16 1.0 = 0x3F80)
  union { ushort us[8]; bf16x8 v; } onesu;
#pragma unroll
  for (int j = 0; j < 8; j++) onesu.us[j] = 0x3F80;
  const bf16x8 ones = onesu.v;

  f32x4 oacc[2][4] = {};
  f32x4 lacc[2] = {};
  float mrun[2] = {-INFINITY, -INFINITY};  // log2 domain

  constexpr int NT = Nn / 64;              // 32 kv tiles
  STAGE(0, 0);                             // prefetch tile 0
  STAGE(1, 64);                            // prefetch tile 1

  int cur = 0;
  for (int t = 0; t < NT; ++t) {
    // tile-t data ready; tile-(t+1)'s 4 loads stay in flight
    if (t < NT - 1) asm volatile("s_waitcnt vmcnt(4)" ::: "memory");
    else            asm volatile("s_waitcnt vmcnt(0)" ::: "memory");
    __builtin_amdgcn_s_barrier();          // data-ready + WAR guard in one
    asm volatile("" ::: "memory");
    if (t + 2 < NT) {
      int sb = cur - 1; if (sb < 0) sb += 3;   // (cur+2)%3
      STAGE(sb, (t + 2) * 64);             // depth-2 prefetch
    }

    const ushort* Kc = &Ks[cur][0];
    const ushort* Vc = &Vs[cur][0];

    // S^T[kv][q] = K * Q^T
    f32x4 sacc[2][4] = {};
    __builtin_amdgcn_s_setprio(1);
#pragma unroll
    for (int kc = 0; kc < 2; kc++) {
#pragma unroll
      for (int jc = 0; jc < 4; jc++) {
        int row = jc * 16 + l16;
        bf16x8 kf = *(const bf16x8*)(Kc + row * 64 + ((kc * 32 + g * 8) ^ ((row & 7) << 3)));
        sacc[0][jc] = __builtin_amdgcn_mfma_f32_16x16x32_bf16(kf, qf[0][kc], sacc[0][jc], 0, 0, 0);
        sacc[1][jc] = __builtin_amdgcn_mfma_f32_16x16x32_bf16(kf, qf[1][kc], sacc[1][jc], 0, 0, 0);
      }
    }
    __builtin_amdgcn_s_setprio(0);

    // online softmax (log2 domain); lane owns q-col = qh*16+l16
    float pmax[2];
#pragma unroll
    for (int qh = 0; qh < 2; qh++) {
      float mj0 = fmaxf(fmaxf(fmaxf(sacc[qh][0][0], sacc[qh][0][1]), sacc[qh][0][2]), sacc[qh][0][3]);
      float mj1 = fmaxf(fmaxf(fmaxf(sacc[qh][1][0], sacc[qh][1][1]), sacc[qh][1][2]), sacc[qh][1][3]);
      float mj2 = fmaxf(fmaxf(fmaxf(sacc[qh][2][0], sacc[qh][2][1]), sacc[qh][2][2]), sacc[qh][2][3]);
      float mj3 = fmaxf(fmaxf(fmaxf(sacc[qh][3][0], sacc[qh][3][1]), sacc[qh][3][2]), sacc[qh][3][3]);
      float mx = fmaxf(fmaxf(fmaxf(mj0, mj1), mj2), mj3);
      mx = fmaxf(mx, __shfl_xor(mx, 16));
      mx = fmaxf(mx, __shfl_xor(mx, 32));
      pmax[qh] = mx * SL2;
    }
    bool need = (pmax[0] > mrun[0] + 8.f) || (pmax[1] > mrun[1] + 8.f);
    if (__any(need)) {
#pragma unroll
      for (int qh = 0; qh < 2; qh++) {
        float mnew = fmaxf(mrun[qh], pmax[qh]);
        float alpha = exp2v(mrun[qh] - mnew);
        mrun[qh] = mnew;
#pragma unroll
        for (int r = 0; r < 4; r++) {
          float ar = __shfl(alpha, g * 4 + r);
#pragma unroll
          for (int dc = 0; dc < 4; dc++) oacc[qh][dc][r] *= ar;
          lacc[qh][r] *= ar;
        }
      }
    }

    // exp2 + pack to bf16 pairs + in-register transpose to PV A-fragments
    bf16x8 pa[2][2];
#pragma unroll
    for (int qh = 0; qh < 2; qh++) {
      uint pk_[4][2];
#pragma unroll
      for (int jc = 0; jc < 4; jc++) {
        float p0 = exp2v(fmaf(sacc[qh][jc][0], SL2, -mrun[qh]));
        float p1 = exp2v(fmaf(sacc[qh][jc][1], SL2, -mrun[qh]));
        float p2 = exp2v(fmaf(sacc[qh][jc][2], SL2, -mrun[qh]));
        float p3 = exp2v(fmaf(sacc[qh][jc][3], SL2, -mrun[qh]));
        asm("v_cvt_pk_bf16_f32 %0, %1, %2" : "=v"(pk_[jc][0]) : "v"(p0), "v"(p1));
        asm("v_cvt_pk_bf16_f32 %0, %1, %2" : "=v"(pk_[jc][1]) : "v"(p2), "v"(p3));
      }
#pragma unroll
      for (int kc = 0; kc < 2; kc++) {
        uint a0 = pk_[kc * 2][0], b0 = pk_[kc * 2 + 1][0];
        asm("v_permlane32_swap_b32 %0, %1" : "+v"(a0), "+v"(b0));
        asm("v_permlane16_swap_b32 %0, %1" : "+v"(a0), "+v"(b0));
        uint a1 = pk_[kc * 2][1], b1 = pk_[kc * 2 + 1][1];
        asm("v_permlane32_swap_b32 %0, %1" : "+v"(a1), "+v"(b1));
        asm("v_permlane16_swap_b32 %0, %1" : "+v"(a1), "+v"(b1));
        union { uint4 u; bf16x8 v; } cv;
        cv.u.x = a0; cv.u.y = a1; cv.u.z = b0; cv.u.w = b1;
        pa[qh][kc] = cv.v;
      }
    }

    // O[q][d] += P[q][kv] * Vt[d][kv]^T ; l += P * ones
    __builtin_amdgcn_s_setprio(1);
#pragma unroll
    for (int kc = 0; kc < 2; kc++) {
#pragma unroll
      for (int dc = 0; dc < 4; dc++) {
        int row = dc * 16 + l16;
        bf16x8 vf = *(const bf16x8*)(Vc + row * 64 + ((kc * 32 + g * 8) ^ ((row & 7) << 3)));
        oacc[0][dc] = __builtin_amdgcn_mfma_f32_16x16x32_bf16(pa[0][kc], vf, oacc[0][dc], 0, 0, 0);
        oacc[1][dc] = __builtin_amdgcn_mfma_f32_16x16x32_bf16(pa[1][kc], vf, oacc[1][dc], 0, 0, 0);
      }
      lacc[0] = __builtin_amdgcn_mfma_f32_16x16x32_bf16(pa[0][kc], ones, lacc[0], 0, 0, 0);
      lacc[1] = __builtin_amdgcn_mfma_f32_16x16x32_bf16(pa[1][kc], ones, lacc[1], 0, 0, 0);
    }
    __builtin_amdgcn_s_setprio(0);

    cur = (cur == 2) ? 0 : cur + 1;
  }
#undef STAGE

  // epilogue: lacc[qh][r] is l for q-row g*4+r -- same domain as oacc rows
#pragma unroll
  for (int qh = 0; qh < 2; qh++) {
    f32x4 linv;
#pragma unroll
    for (int r = 0; r < 4; r++) linv[r] = 1.f / lacc[qh][r];
#pragma unroll
    for (int r = 0; r < 4; r++) {
      int grow = b * Nn + q0 + qh * 16 + g * 4 + r;
      ushort* op = obf + (size_t)grow * Cc + h * 64 + l16;
#pragma unroll
      for (int dc = 0; dc < 4; dc++)
        op[dc * 16] = f2bf(oacc[qh][dc][r] * linv[r]);
    }
  }
}

// ---------------------------------------------------------------------------
extern "C" void kernel_launch(void* const* d_in, const int* in_sizes, int n_in,
                              void* d_out, int out_size, void* d_ws, size_t ws_size,
                              hipStream_t stream) {
  const float* x      = (const float*)d_in[0];
  const float* w_qkv  = (const float*)d_in[1];
  const float* w_proj = (const float*)d_in[2];
  const float* b_proj = (const float*)d_in[3];
  float* out = (float*)d_out;

  char* ws = (char*)d_ws;
  ushort* Xbf    = (ushort*)(ws);                        // 16.8 MB
  ushort* WqkvT  = (ushort*)(ws + (16u << 20));          // 6.3 MB
  ushort* WprojT = (ushort*)(ws + (22u << 20));          // 2.1 MB
  ushort* QKbf   = (ushort*)(ws + (24u << 20));          // 33.6 MB
  ushort* Vtg    = (ushort*)(ws + (56u << 20));          // 16.8 MB
  ushort* Obf    = (ushort*)(ws + (72u << 20));          // 16.8 MB (ends 88 MB)

  cvt_bf16_kernel<<<4096, 256, 0, stream>>>(x, Xbf);
  transpose_cvt_kernel<<<dim3(QKVC / 64, Cc / 64), 256, 0, stream>>>(w_qkv, WqkvT, Cc, QKVC);
  transpose_cvt_kernel<<<dim3(Cc / 64, Cc / 64), 256, 0, stream>>>(w_proj, WprojT, Cc, Cc);
  gemm128_kernel<0><<<dim3(QKVC / 128, ROWS / 128), 256, 0, stream>>>(
      Xbf, WqkvT, QKbf, Vtg, nullptr, ROWS, QKVC, Cc);
  flash_mfma_kernel<<<dim3(Nn / 128, Bn * Hh), 256, 0, stream>>>(QKbf, Vtg, Obf);
  gemm128_kernel<1><<<dim3(Cc / 128, ROWS / 128), 256, 0, stream>>>(
      Obf, WprojT, out, nullptr, b_proj, ROWS, Cc, Cc);
}

// Round 6
// 239.208 us; speedup vs baseline: 1.0523x; 1.0272x over previous
//
#include <hip/hip_runtime.h>
#include <hip/hip_bf16.h>
#include <cstdint>
#include <cstddef>

typedef unsigned int uint;
typedef unsigned short ushort;

constexpr int Bn = 4, Nn = 2048, Cc = 1024, Hh = 16;
constexpr int ROWS = Bn * Nn;           // 8192
constexpr int QKVC = 3 * Cc;            // 3072
constexpr float SL2 = 0.18033688011118f; // D^-0.5 * log2(e)

typedef __bf16 bf16_t;
typedef bf16_t bf16x8 __attribute__((ext_vector_type(8)));
typedef float f32x4 __attribute__((ext_vector_type(4)));

__device__ __forceinline__ ushort f2bf(float f) {
  union { __bf16 b; ushort u; } cv;
  cv.b = (__bf16)f;
  return cv.u;
}
__device__ __forceinline__ float exp2v(float x) { return __builtin_exp2f(x); }

__device__ __forceinline__ void gload_lds16(const void* g, void* l) {
  __builtin_amdgcn_global_load_lds(
      (const __attribute__((address_space(1))) void*)g,
      (__attribute__((address_space(3))) void*)l, 16, 0, 0);
}

// ---------------- f32 -> bf16 elementwise (8 elems/thread, exact cover) ----
__global__ __launch_bounds__(256) void cvt_bf16_kernel(
    const float* __restrict__ in, ushort* __restrict__ out) {
  int i = blockIdx.x * 256 + threadIdx.x;
  const float4* ip = (const float4*)in;
  float4 a = ip[i * 2], b = ip[i * 2 + 1];
  uint4 w;
  w.x = (uint)f2bf(a.x) | ((uint)f2bf(a.y) << 16);
  w.y = (uint)f2bf(a.z) | ((uint)f2bf(a.w) << 16);
  w.z = (uint)f2bf(b.x) | ((uint)f2bf(b.y) << 16);
  w.w = (uint)f2bf(b.z) | ((uint)f2bf(b.w) << 16);
  ((uint4*)out)[i] = w;
}

// ---------------- transpose + convert: W[K][N] f32 -> Wt[N][K] bf16 --------
__global__ __launch_bounds__(256) void transpose_cvt_kernel(
    const float* __restrict__ W, ushort* __restrict__ Wt, int K, int N) {
  __shared__ float tile[64][65];
  const int n0 = blockIdx.x * 64, k0 = blockIdx.y * 64;
  const int tid = threadIdx.x;
#pragma unroll
  for (int it = 0; it < 16; it++) {
    int idx = tid + it * 256;
    int r = idx >> 6, c = idx & 63;
    tile[r][c] = W[(size_t)(k0 + r) * N + n0 + c];
  }
  __syncthreads();
#pragma unroll
  for (int it = 0; it < 16; it++) {
    int idx = tid + it * 256;
    int r = idx >> 6, c = idx & 63;
    Wt[(size_t)(n0 + r) * K + k0 + c] = f2bf(tile[c][r]);
  }
}

// ---------------- 128x128 MFMA GEMM (m97 structure): C = A * Bt^T -----------
template <int MODE>
__global__ __launch_bounds__(256) void gemm128_kernel(
    const ushort* __restrict__ A, const ushort* __restrict__ Bt,
    void* __restrict__ Cout, void* __restrict__ Vout,
    const float* __restrict__ bias, int M, int N, int K) {
  __shared__ ushort As[128 * 32];
  __shared__ ushort Bs[128 * 32];
  const int tid = threadIdx.x;
  const int lane = tid & 63;
  const int wid = tid >> 6;
  const int wm = wid >> 1, wn = wid & 1;          // 2x2 wave grid
  const int l16 = lane & 15, g = lane >> 4;
  const int n0 = blockIdx.x * 128, m0 = blockIdx.y * 128;

  const int c0 = tid, c1 = tid + 256;
  const ushort* Ab = A + (size_t)m0 * K;
  const ushort* Bb = Bt + (size_t)n0 * K;
  f32x4 acc[4][4] = {};

  for (int k0 = 0; k0 < K; k0 += 32) {
    gload_lds16(Ab + (size_t)(c0 >> 2) * K + k0 + (c0 & 3) * 8, As + c0 * 8);
    gload_lds16(Ab + (size_t)(c1 >> 2) * K + k0 + (c1 & 3) * 8, As + c1 * 8);
    gload_lds16(Bb + (size_t)(c0 >> 2) * K + k0 + (c0 & 3) * 8, Bs + c0 * 8);
    gload_lds16(Bb + (size_t)(c1 >> 2) * K + k0 + (c1 & 3) * 8, Bs + c1 * 8);
    __syncthreads();
    bf16x8 af[4], bfr[4];
#pragma unroll
    for (int mf = 0; mf < 4; mf++)
      af[mf] = *(const bf16x8*)(As + (wm * 64 + mf * 16 + l16) * 32 + g * 8);
#pragma unroll
    for (int nf = 0; nf < 4; nf++)
      bfr[nf] = *(const bf16x8*)(Bs + (wn * 64 + nf * 16 + l16) * 32 + g * 8);
#pragma unroll
    for (int mf = 0; mf < 4; mf++)
#pragma unroll
      for (int nf = 0; nf < 4; nf++)
        acc[mf][nf] = __builtin_amdgcn_mfma_f32_16x16x32_bf16(af[mf], bfr[nf], acc[mf][nf], 0, 0, 0);
    __syncthreads();
  }

#pragma unroll
  for (int mf = 0; mf < 4; mf++) {
    const int orow0 = m0 + wm * 64 + mf * 16 + g * 4;
#pragma unroll
    for (int nf = 0; nf < 4; nf++) {
      int col = n0 + wn * 64 + nf * 16 + l16;
      if (MODE == 0) {
        if (col < 2048) {
#pragma unroll
          for (int r = 0; r < 4; r++)
            ((ushort*)Cout)[(size_t)(orow0 + r) * 2048 + col] = f2bf(acc[mf][nf][r]);
        } else {
          int hh = (col - 2048) >> 6, dd = (col - 2048) & 63;
          int bb = orow0 >> 11, nn = orow0 & 2047;
          ushort4 w;
          w.x = f2bf(acc[mf][nf][0]); w.y = f2bf(acc[mf][nf][1]);
          w.z = f2bf(acc[mf][nf][2]); w.w = f2bf(acc[mf][nf][3]);
          *(ushort4*)((ushort*)Vout + ((size_t)(bb * 16 + hh) * 64 + dd) * 2048 + nn) = w;
        }
      } else {
#pragma unroll
        for (int r = 0; r < 4; r++)
          ((float*)Cout)[(size_t)(orow0 + r) * N + col] = acc[mf][nf][r] + bias[col];
      }
    }
  }
}

// ---------------- MFMA flash attention (QBLK=32, dbuf depth-1, XCD) ---------
// qk:  bf16 [8192][2048]  (cols 0-1023 Q, 1024-2047 K; col = h*64+d)
// vt:  bf16 [64 bh][64 d][2048 n]
// obf: bf16 [8192][1024]
//
// R2 compute structure (in-register P via cvt_pk + permlane swaps, l via
// mfma(pa,ones); 32 KB LDS double-buffer, 1 barrier/tile) + XCD-aware
// bijective remap (staging loads become L2 hits -> depth-1 prefetch is
// sufficient). Max-reduce uses __shfl_xor (proven); the permlane-swap
// max-reduce from R5 was reverted: with both "+v" operands holding the
// SAME value the allocator may alias them to one VGPR and the swap no-ops.
__global__ __launch_bounds__(256, 4) void flash_mfma_kernel(
    const ushort* __restrict__ qk, const ushort* __restrict__ vt,
    ushort* __restrict__ obf) {
  __shared__ ushort Ks[2][64 * 64];       // double-buffered [kv][d], swizzled
  __shared__ ushort Vs[2][64 * 64];       // double-buffered [d][kv], swizzled
  const int tid = threadIdx.x;
  const int lane = tid & 63, wid = tid >> 6;
  const int l16 = lane & 15, g = lane >> 4;

  // XCD-aware bijective remap: grid (16, 64); HW round-robins flat id across
  // 8 XCDs (xcd ~ f&7): give each XCD 8 whole bh values -> K/V L2-resident.
  const int f = blockIdx.x + (int)(gridDim.x * blockIdx.y);
  const int xcd = f & 7, slot = f >> 3;
  const int bh = xcd * 8 + (slot >> 4);
  const int qx = slot & 15;
  const int b = bh >> 4, h = bh & 15;
  const int q0 = qx * 128 + wid * 32;

  // staging chunk ids (c in [0,512): row=c>>3, colc=c&7, XOR-swizzled source)
  const int sc0 = tid, sc1 = tid + 256;
  const int sr0 = sc0 >> 3, scol0 = ((sc0 & 7) ^ (sr0 & 7)) * 8;
  const int sr1 = sc1 >> 3, scol1 = ((sc1 & 7) ^ (sr1 & 7)) * 8;
  const ushort* Kbase = qk + (size_t)b * Nn * 2048 + 1024 + h * 64;
  const ushort* Vbase = vt + (size_t)bh * 64 * 2048;

#define STAGE(buf, kv0)                                                       \
  do {                                                                        \
    gload_lds16(Kbase + (size_t)((kv0) + sr0) * 2048 + scol0,                 \
                &Ks[buf][0] + sc0 * 8);                                       \
    gload_lds16(Kbase + (size_t)((kv0) + sr1) * 2048 + scol1,                 \
                &Ks[buf][0] + sc1 * 8);                                       \
    gload_lds16(Vbase + (size_t)sr0 * 2048 + (kv0) + scol0,                   \
                &Vs[buf][0] + sc0 * 8);                                       \
    gload_lds16(Vbase + (size_t)sr1 * 2048 + (kv0) + scol1,                   \
                &Vs[buf][0] + sc1 * 8);                                       \
  } while (0)

  // hoist Q fragments
  bf16x8 qf[2][2];
#pragma unroll
  for (int qh = 0; qh < 2; qh++)
#pragma unroll
    for (int kc = 0; kc < 2; kc++)
      qf[qh][kc] = *(const bf16x8*)(
          qk + (size_t)(b * Nn + q0 + qh * 16 + l16) * 2048 + h * 64 + kc * 32 + g * 8);

  // ones B-fragment (bf16 1.0 = 0x3F80)
  union { ushort us[8]; bf16x8 v; } onesu;
#pragma unroll
  for (int j = 0; j < 8; j++) onesu.us[j] = 0x3F80;
  const bf16x8 ones = onesu.v;

  f32x4 oacc[2][4] = {};
  f32x4 lacc[2] = {};
  float mrun[2] = {-INFINITY, -INFINITY};  // log2 domain

  STAGE(0, 0);                             // prefetch tile 0

  for (int t = 0; t < Nn / 64; ++t) {
    const int cur = t & 1;
    // tile-t loads were issued a full tile ago; L2-hit latency -> ~free wait
    asm volatile("s_waitcnt vmcnt(0)" ::: "memory");
    __builtin_amdgcn_s_barrier();          // data-ready + WAR guard in one
    asm volatile("" ::: "memory");
    if (t < Nn / 64 - 1) STAGE(cur ^ 1, (t + 1) * 64);  // overlaps whole tile

    const ushort* Kc = &Ks[cur][0];
    const ushort* Vc = &Vs[cur][0];

    // S^T[kv][q] = K * Q^T
    f32x4 sacc[2][4] = {};
    __builtin_amdgcn_s_setprio(1);
#pragma unroll
    for (int kc = 0; kc < 2; kc++) {
#pragma unroll
      for (int jc = 0; jc < 4; jc++) {
        int row = jc * 16 + l16;
        bf16x8 kf = *(const bf16x8*)(Kc + row * 64 + ((kc * 32 + g * 8) ^ ((row & 7) << 3)));
        sacc[0][jc] = __builtin_amdgcn_mfma_f32_16x16x32_bf16(kf, qf[0][kc], sacc[0][jc], 0, 0, 0);
        sacc[1][jc] = __builtin_amdgcn_mfma_f32_16x16x32_bf16(kf, qf[1][kc], sacc[1][jc], 0, 0, 0);
      }
    }
    __builtin_amdgcn_s_setprio(0);

    // online softmax (log2 domain); lane owns q-col = qh*16+l16
    float pmax[2];
#pragma unroll
    for (int qh = 0; qh < 2; qh++) {
      float mj0 = fmaxf(fmaxf(fmaxf(sacc[qh][0][0], sacc[qh][0][1]), sacc[qh][0][2]), sacc[qh][0][3]);
      float mj1 = fmaxf(fmaxf(fmaxf(sacc[qh][1][0], sacc[qh][1][1]), sacc[qh][1][2]), sacc[qh][1][3]);
      float mj2 = fmaxf(fmaxf(fmaxf(sacc[qh][2][0], sacc[qh][2][1]), sacc[qh][2][2]), sacc[qh][2][3]);
      float mj3 = fmaxf(fmaxf(fmaxf(sacc[qh][3][0], sacc[qh][3][1]), sacc[qh][3][2]), sacc[qh][3][3]);
      float mx = fmaxf(fmaxf(fmaxf(mj0, mj1), mj2), mj3);
      mx = fmaxf(mx, __shfl_xor(mx, 16));
      mx = fmaxf(mx, __shfl_xor(mx, 32));
      pmax[qh] = mx * SL2;
    }
    bool need = (pmax[0] > mrun[0] + 8.f) || (pmax[1] > mrun[1] + 8.f);
    if (__any(need)) {
#pragma unroll
      for (int qh = 0; qh < 2; qh++) {
        float mnew = fmaxf(mrun[qh], pmax[qh]);
        float alpha = exp2v(mrun[qh] - mnew);
        mrun[qh] = mnew;
#pragma unroll
        for (int r = 0; r < 4; r++) {
          float ar = __shfl(alpha, g * 4 + r);
#pragma unroll
          for (int dc = 0; dc < 4; dc++) oacc[qh][dc][r] *= ar;
          lacc[qh][r] *= ar;
        }
      }
    }

    // exp2 + pack to bf16 pairs + in-register transpose to PV A-fragments
    bf16x8 pa[2][2];
#pragma unroll
    for (int qh = 0; qh < 2; qh++) {
      uint pk_[4][2];
#pragma unroll
      for (int jc = 0; jc < 4; jc++) {
        float p0 = exp2v(fmaf(sacc[qh][jc][0], SL2, -mrun[qh]));
        float p1 = exp2v(fmaf(sacc[qh][jc][1], SL2, -mrun[qh]));
        float p2 = exp2v(fmaf(sacc[qh][jc][2], SL2, -mrun[qh]));
        float p3 = exp2v(fmaf(sacc[qh][jc][3], SL2, -mrun[qh]));
        asm("v_cvt_pk_bf16_f32 %0, %1, %2" : "=v"(pk_[jc][0]) : "v"(p0), "v"(p1));
        asm("v_cvt_pk_bf16_f32 %0, %1, %2" : "=v"(pk_[jc][1]) : "v"(p2), "v"(p3));
      }
#pragma unroll
      for (int kc = 0; kc < 2; kc++) {
        uint a0 = pk_[kc * 2][0], b0 = pk_[kc * 2 + 1][0];
        asm("v_permlane32_swap_b32 %0, %1" : "+v"(a0), "+v"(b0));
        asm("v_permlane16_swap_b32 %0, %1" : "+v"(a0), "+v"(b0));
        uint a1 = pk_[kc * 2][1], b1 = pk_[kc * 2 + 1][1];
        asm("v_permlane32_swap_b32 %0, %1" : "+v"(a1), "+v"(b1));
        asm("v_permlane16_swap_b32 %0, %1" : "+v"(a1), "+v"(b1));
        union { uint4 u; bf16x8 v; } cv;
        cv.u.x = a0; cv.u.y = a1; cv.u.z = b0; cv.u.w = b1;
        pa[qh][kc] = cv.v;
      }
    }

    // O[q][d] += P[q][kv] * Vt[d][kv]^T ; l += P * ones
    __builtin_amdgcn_s_setprio(1);
#pragma unroll
    for (int kc = 0; kc < 2; kc++) {
#pragma unroll
      for (int dc = 0; dc < 4; dc++) {
        int row = dc * 16 + l16;
        bf16x8 vf = *(const bf16x8*)(Vc + row * 64 + ((kc * 32 + g * 8) ^ ((row & 7) << 3)));
        oacc[0][dc] = __builtin_amdgcn_mfma_f32_16x16x32_bf16(pa[0][kc], vf, oacc[0][dc], 0, 0, 0);
        oacc[1][dc] = __builtin_amdgcn_mfma_f32_16x16x32_bf16(pa[1][kc], vf, oacc[1][dc], 0, 0, 0);
      }
      lacc[0] = __builtin_amdgcn_mfma_f32_16x16x32_bf16(pa[0][kc], ones, lacc[0], 0, 0, 0);
      lacc[1] = __builtin_amdgcn_mfma_f32_16x16x32_bf16(pa[1][kc], ones, lacc[1], 0, 0, 0);
    }
    __builtin_amdgcn_s_setprio(0);
  }
#undef STAGE

  // epilogue: lacc[qh][r] is l for q-row g*4+r -- same domain as oacc rows
#pragma unroll
  for (int qh = 0; qh < 2; qh++) {
    f32x4 linv;
#pragma unroll
    for (int r = 0; r < 4; r++) linv[r] = 1.f / lacc[qh][r];
#pragma unroll
    for (int r = 0; r < 4; r++) {
      int grow = b * Nn + q0 + qh * 16 + g * 4 + r;
      ushort* op = obf + (size_t)grow * Cc + h * 64 + l16;
#pragma unroll
      for (int dc = 0; dc < 4; dc++)
        op[dc * 16] = f2bf(oacc[qh][dc][r] * linv[r]);
    }
  }
}

// ---------------------------------------------------------------------------
extern "C" void kernel_launch(void* const* d_in, const int* in_sizes, int n_in,
                              void* d_out, int out_size, void* d_ws, size_t ws_size,
                              hipStream_t stream) {
  const float* x      = (const float*)d_in[0];
  const float* w_qkv  = (const float*)d_in[1];
  const float* w_proj = (const float*)d_in[2];
  const float* b_proj = (const float*)d_in[3];
  float* out = (float*)d_out;

  char* ws = (char*)d_ws;
  ushort* Xbf    = (ushort*)(ws);                        // 16.8 MB
  ushort* WqkvT  = (ushort*)(ws + (16u << 20));          // 6.3 MB
  ushort* WprojT = (ushort*)(ws + (22u << 20));          // 2.1 MB
  ushort* QKbf   = (ushort*)(ws + (24u << 20));          // 33.6 MB
  ushort* Vtg    = (ushort*)(ws + (56u << 20));          // 16.8 MB
  ushort* Obf    = (ushort*)(ws + (72u << 20));          // 16.8 MB (ends 88 MB)

  cvt_bf16_kernel<<<4096, 256, 0, stream>>>(x, Xbf);
  transpose_cvt_kernel<<<dim3(QKVC / 64, Cc / 64), 256, 0, stream>>>(w_qkv, WqkvT, Cc, QKVC);
  transpose_cvt_kernel<<<dim3(Cc / 64, Cc / 64), 256, 0, stream>>>(w_proj, WprojT, Cc, Cc);
  gemm128_kernel<0><<<dim3(QKVC / 128, ROWS / 128), 256, 0, stream>>>(
      Xbf, WqkvT, QKbf, Vtg, nullptr, ROWS, QKVC, Cc);
  flash_mfma_kernel<<<dim3(Nn / 128, Bn * Hh), 256, 0, stream>>>(QKbf, Vtg, Obf);
  gemm128_kernel<1><<<dim3(Cc / 128, ROWS / 128), 256, 0, stream>>>(
      Obf, WprojT, out, nullptr, b_proj, ROWS, Cc, Cc);
}